// Round 10
// baseline (60.000 us; speedup 1.0000x reference)
//
#include <hip/hip_runtime.h>
#include <stdint.h>

// AeTransformer_44839458570443: 3-NN inverse-distance interpolation + (tanh+1)/2.
// xyz1: [B,3,N] fp32, xyz2: [B,3,S] fp32, points2: [B,1,S] fp32 -> out [B,N] fp32.
//
// Selection bit-matches the reference fp32 expanded distance
//   d = (-2*((x*x'+y*y')+z*z') + ||q||^2) + ||p||^2   (fp32, no FMA)
// ordered by (d, index).
// R6 structure (1 query/thread, 16 waves/CU) was LDS-PIPE-BOUND: 8192
// broadcast ds_read_b128/CU x 12cyc ~= 41us ~= measured. Round 10 splits the
// candidate scan across TWO pipes: groups 0-31 from LDS (lgkmcnt/LDS pipe),
// groups 32-63 from global/L1 (vmcnt/TA pipe; address laundered through a
// VGPR so it cannot scalarize to s_load, which would share lgkmcnt with
// ds_read). LDS serial time halves; TA path runs concurrently.
// PHASE A (proxy): per group of 8, FMA distances + min tree -> group min;
//   keep 5 best (group-min | gid) keys (lemma: at most 3 groups can have
//   min <= d3; 5 kept for proxy margin).
// PHASE C (global/L1 divergent gathers; R8: zero bank conflicts): FMA-proxy
//   rescan of the 40 survivors, 9-bit-quantized 6-slot screen (proven R3),
//   exact replicated ref_d on 6, (d,idx) sort, replicated fp32 weight chain.
static constexpr int B = 4;
static constexpr int N = 65536;
static constexpr int S = 512;

__global__ __launch_bounds__(256) void prep_kernel(const float* __restrict__ xyz2,
                                                   float4* __restrict__ ws) {
    int t = blockIdx.x * 256 + threadIdx.x;
    if (t >= B * S) return;
    int b = t >> 9, s = t & 511;
    const float* p = xyz2 + (size_t)b * 3 * S;
    float x = p[s], y = p[s + S], z = p[s + 2 * S];
    float c = __fadd_rn(__fadd_rn(__fmul_rn(x, x), __fmul_rn(y, y)), __fmul_rn(z, z));
    ws[t] = make_float4(x, y, z, c);
}

// Reference-replicated fp32 distance (numpy order, no contraction)
__device__ __forceinline__ float ref_d(float x1, float y1, float z1, float ssrc, float4 p) {
    float dot = __fadd_rn(__fadd_rn(__fmul_rn(x1, p.x), __fmul_rn(y1, p.y)),
                          __fmul_rn(z1, p.z));
    float t = __fmul_rn(dot, -2.0f);
    return __fadd_rn(__fadd_rn(t, ssrc), p.w);
}

#define CAS(da_, ia_, db_, ib_)                                     \
    {                                                               \
        bool sw_ = (db_ < da_) || ((db_ == da_) && (ib_ < ia_));    \
        float tda_ = sw_ ? db_ : da_;                               \
        int tia_ = sw_ ? ib_ : ia_;                                 \
        db_ = sw_ ? da_ : db_;                                      \
        ib_ = sw_ ? ia_ : ib_;                                      \
        da_ = tda_;                                                 \
        ia_ = tia_;                                                 \
    }

#define INS5(k)                                                     \
    {                                                               \
        float t4 = __builtin_amdgcn_fmed3f(g3, (k), g4);            \
        float t3 = __builtin_amdgcn_fmed3f(g2, (k), g3);            \
        float t2 = __builtin_amdgcn_fmed3f(g1, (k), g2);            \
        float t1 = __builtin_amdgcn_fmed3f(g0, (k), g1);            \
        g0 = fminf(g0, (k));                                        \
        g1 = t1; g2 = t2; g3 = t3; g4 = t4;                         \
    }

#define INS6(k)                                                     \
    {                                                               \
        float t5 = __builtin_amdgcn_fmed3f(m4, (k), m5);            \
        float t4 = __builtin_amdgcn_fmed3f(m3, (k), m4);            \
        float t3 = __builtin_amdgcn_fmed3f(m2, (k), m3);            \
        float t2 = __builtin_amdgcn_fmed3f(m1, (k), m2);            \
        float t1 = __builtin_amdgcn_fmed3f(m0, (k), m1);            \
        m0 = fminf(m0, (k));                                        \
        m1 = t1; m2 = t2; m3 = t3; m4 = t4; m5 = t5;                \
    }

// Phase-A group processing for 8 candidates already loaded into buf[]
#define PROC_GROUP(buf, gid)                                                  \
    {                                                                         \
        float e[8];                                                           \
        _Pragma("unroll") for (int j = 0; j < 8; ++j)                         \
            e[j] = fmaf(nx2, buf[j].x,                                        \
                        fmaf(ny2, buf[j].y, fmaf(nz2, buf[j].z, buf[j].w)));  \
        float mA = fminf(fminf(e[0], e[1]), e[2]);                            \
        float mB = fminf(fminf(e[3], e[4]), e[5]);                            \
        float mC = fminf(fminf(mA, mB), e[6]);                                \
        float gm = fminf(mC, e[7]);                                           \
        float gkey = __uint_as_float(                                         \
            (__float_as_uint(gm + c) & 0xFFFFFFC0u) | (uint32_t)(gid));       \
        INS5(gkey);                                                           \
    }

__global__ __launch_bounds__(256, 4) void knn3_kernel(const float* __restrict__ xyz1,
                                                      const float* __restrict__ points2,
                                                      const float4* __restrict__ ws,
                                                      float* __restrict__ out) {
    __shared__ float4 tile[256];  // 4 KB: groups 0-31 only (LDS-pipe half)
    const int tid = threadIdx.x;
    const int b = blockIdx.x >> 8;               // 256 blocks per batch
    const int n = ((blockIdx.x & 255) << 8) | tid;

    const float4* __restrict__ wsrc = ws + b * S;
    tile[tid] = wsrc[tid];
    __syncthreads();

    const float* q = xyz1 + (size_t)b * 3 * N;
    float x1 = q[n], y1 = q[n + N], z1 = q[n + 2 * N];
    float ssrc = __fadd_rn(__fadd_rn(__fmul_rn(x1, x1), __fmul_rn(y1, y1)),
                           __fmul_rn(z1, z1));
    // screen-only constants (proxy zone; phase C refine is exact)
    float c = ssrc + 0.25f;  // bias keeps packed keys > 0
    float nx2 = -2.0f * x1, ny2 = -2.0f * y1, nz2 = -2.0f * z1;

    // ---- Phase A: dual-pipe group scan; keep 5 best (min | gid) keys ----
    float g0 = 3.0e38f, g1 = 3.0e38f, g2 = 3.0e38f, g3 = 3.0e38f, g4 = 3.0e38f;
#pragma unroll 2
    for (int g = 0; g < 32; ++g) {
        // global half first (long latency; TA pipe / vmcnt). Launder the
        // uniform offset through a VGPR so it can't become s_load (lgkmcnt).
        int goff = (g + 32) << 3;
        asm volatile("" : "+v"(goff));
        float4 pG[8];
#pragma unroll
        for (int j = 0; j < 8; ++j) pG[j] = wsrc[goff + j];
        // LDS half (lgkmcnt / LDS pipe)
        float4 pL[8];
#pragma unroll
        for (int j = 0; j < 8; ++j) pL[j] = tile[g * 8 + j];
        PROC_GROUP(pL, g);
        PROC_GROUP(pG, g + 32);
    }

    // ---- Phase C: global/L1 divergent gathers; proxy 6-slot screen ----
    float m0 = 3.0e38f, m1 = 3.0e38f, m2 = 3.0e38f,
          m3 = 3.0e38f, m4 = 3.0e38f, m5 = 3.0e38f;
    float gkeys[5] = {g0, g1, g2, g3, g4};
#pragma unroll
    for (int t = 0; t < 5; ++t) {
        int gbase = (int)(__float_as_uint(gkeys[t]) & 63u) << 3;
#pragma unroll
        for (int j = 0; j < 8; ++j) {
            float4 p = wsrc[gbase + j];  // divergent gather, L1-resident
            float e2 = fmaf(nx2, p.x,
                            fmaf(ny2, p.y, fmaf(nz2, p.z, p.w + c)));
            float k = __uint_as_float((__float_as_uint(e2) & 0xFFFFFE00u) |
                                      (uint32_t)(gbase + j));
            INS6(k);
        }
    }

    // ---- Refine: re-score 6 survivors exactly, sort by (d, idx) ----
    int gi[6];
    float dd[6];
    gi[0] = (int)(__float_as_uint(m0) & 511u);
    gi[1] = (int)(__float_as_uint(m1) & 511u);
    gi[2] = (int)(__float_as_uint(m2) & 511u);
    gi[3] = (int)(__float_as_uint(m3) & 511u);
    gi[4] = (int)(__float_as_uint(m4) & 511u);
    gi[5] = (int)(__float_as_uint(m5) & 511u);
#pragma unroll
    for (int j = 0; j < 6; ++j) dd[j] = ref_d(x1, y1, z1, ssrc, wsrc[gi[j]]);

#pragma unroll
    for (int pp = 0; pp < 3; ++pp)
#pragma unroll
        for (int i = 4; i >= pp; --i) CAS(dd[i], gi[i], dd[i + 1], gi[i + 1]);

    // Replicate reference weight/interp chain in fp32, nearest-first order
    const float EPS32 = 1e-8f;
    float r0 = __fdiv_rn(1.0f, __fadd_rn(dd[0], EPS32));
    float r1 = __fdiv_rn(1.0f, __fadd_rn(dd[1], EPS32));
    float r2 = __fdiv_rn(1.0f, __fadd_rn(dd[2], EPS32));
    float rs = __fadd_rn(__fadd_rn(r0, r1), r2);
    float w0 = __fdiv_rn(r0, rs);
    float w1 = __fdiv_rn(r1, rs);
    float w2 = __fdiv_rn(r2, rs);
    const float* f = points2 + (size_t)b * S;  // D = 1
    float interp = __fadd_rn(__fadd_rn(__fmul_rn(f[gi[0]], w0), __fmul_rn(f[gi[1]], w1)),
                             __fmul_rn(f[gi[2]], w2));
    float t = tanhf(interp);
    out[((size_t)b << 16) | (uint32_t)n] = __fmul_rn(__fadd_rn(t, 1.0f), 0.5f);
}

extern "C" void kernel_launch(void* const* d_in, const int* in_sizes, int n_in,
                              void* d_out, int out_size, void* d_ws, size_t ws_size,
                              hipStream_t stream) {
    const float* xyz1 = (const float*)d_in[0];
    const float* xyz2 = (const float*)d_in[1];
    const float* points2 = (const float*)d_in[2];
    float* out = (float*)d_out;
    float4* ws = (float4*)d_ws;  // B*S*16 = 32 KB

    prep_kernel<<<(B * S + 255) / 256, 256, 0, stream>>>(xyz2, ws);
    knn3_kernel<<<(B * N) / 256, 256, 0, stream>>>(xyz1, points2, ws, out);
}

// Round 11
// 44.369 us; speedup vs baseline: 1.3523x; 1.3523x over previous
//
#include <hip/hip_runtime.h>
#include <stdint.h>

// AeTransformer_44839458570443: 3-NN inverse-distance interpolation + (tanh+1)/2.
// xyz1: [B,3,N] fp32, xyz2: [B,3,S] fp32, points2: [B,1,S] fp32 -> out [B,N] fp32.
//
// Selection bit-matches the reference fp32 expanded distance
//   d = (-2*((x*x'+y*y')+z*z') + ||q||^2) + ||p||^2   (fp32, no FMA)
// ordered by (d, index).
//
// R6 was LDS-pipe-bound (8192 broadcast ds_read_b128/CU x 12cyc ~= 41us ~=
// measured 39us). Round 11 feeds phase A from the SCALAR path instead: the
// candidate table address is wave-uniform (laundered via readfirstlane), so
// the loads compile to s_load_dwordx16 through K$ (lgkmcnt, scalar pipe) --
// zero LDS traffic, zero vector-memory traffic in the scan. VALU does ~42
// inst/group (group-min screen, R6-proven): ~9us/SIMD at 4 waves/SIMD.
// PHASE A (proxy): per group of 8, 3-FMA distances + min tree -> group min;
//   keep 5 best (group-min | gid) keys. Lemma: at most 3 groups can have
//   min <= d3 -> top-3 lives in best-3 groups; 5 kept for proxy margin.
// PHASE C (global/L1 divergent gathers; R8/R10-proven, 0 bank conflicts):
//   FMA-proxy rescan of the 40 survivors, 9-bit-quantized 6-slot screen,
//   exact replicated ref_d on 6, (d,idx) sort, replicated fp32 weight chain.
static constexpr int B = 4;
static constexpr int N = 65536;
static constexpr int S = 512;

__global__ __launch_bounds__(256) void prep_kernel(const float* __restrict__ xyz2,
                                                   float4* __restrict__ ws) {
    int t = blockIdx.x * 256 + threadIdx.x;
    if (t >= B * S) return;
    int b = t >> 9, s = t & 511;
    const float* p = xyz2 + (size_t)b * 3 * S;
    float x = p[s], y = p[s + S], z = p[s + 2 * S];
    float c = __fadd_rn(__fadd_rn(__fmul_rn(x, x), __fmul_rn(y, y)), __fmul_rn(z, z));
    ws[t] = make_float4(x, y, z, c);
}

// Reference-replicated fp32 distance (numpy order, no contraction)
__device__ __forceinline__ float ref_d(float x1, float y1, float z1, float ssrc, float4 p) {
    float dot = __fadd_rn(__fadd_rn(__fmul_rn(x1, p.x), __fmul_rn(y1, p.y)),
                          __fmul_rn(z1, p.z));
    float t = __fmul_rn(dot, -2.0f);
    return __fadd_rn(__fadd_rn(t, ssrc), p.w);
}

#define CAS(da_, ia_, db_, ib_)                                     \
    {                                                               \
        bool sw_ = (db_ < da_) || ((db_ == da_) && (ib_ < ia_));    \
        float tda_ = sw_ ? db_ : da_;                               \
        int tia_ = sw_ ? ib_ : ia_;                                 \
        db_ = sw_ ? da_ : db_;                                      \
        ib_ = sw_ ? ia_ : ib_;                                      \
        da_ = tda_;                                                 \
        ia_ = tia_;                                                 \
    }

#define INS5(k)                                                     \
    {                                                               \
        float t4 = __builtin_amdgcn_fmed3f(g3, (k), g4);            \
        float t3 = __builtin_amdgcn_fmed3f(g2, (k), g3);            \
        float t2 = __builtin_amdgcn_fmed3f(g1, (k), g2);            \
        float t1 = __builtin_amdgcn_fmed3f(g0, (k), g1);            \
        g0 = fminf(g0, (k));                                        \
        g1 = t1; g2 = t2; g3 = t3; g4 = t4;                         \
    }

#define INS6(k)                                                     \
    {                                                               \
        float t5 = __builtin_amdgcn_fmed3f(m4, (k), m5);            \
        float t4 = __builtin_amdgcn_fmed3f(m3, (k), m4);            \
        float t3 = __builtin_amdgcn_fmed3f(m2, (k), m3);            \
        float t2 = __builtin_amdgcn_fmed3f(m1, (k), m2);            \
        float t1 = __builtin_amdgcn_fmed3f(m0, (k), m1);            \
        m0 = fminf(m0, (k));                                        \
        m1 = t1; m2 = t2; m3 = t3; m4 = t4; m5 = t5;                \
    }

__global__ __launch_bounds__(256, 4) void knn3_kernel(const float* __restrict__ xyz1,
                                                      const float* __restrict__ points2,
                                                      const float4* __restrict__ ws,
                                                      float* __restrict__ out) {
    const int tid = threadIdx.x;
    const int b = blockIdx.x >> 8;               // 256 blocks per batch
    const int n = ((blockIdx.x & 255) << 8) | tid;

    // Wave-uniform table base, laundered so uniformity analysis selects the
    // scalar (s_load / K$) path for the phase-A reads.
    const int b_u = __builtin_amdgcn_readfirstlane(b);
    const float4* __restrict__ wtab = ws + (size_t)b_u * S;  // uniform scan
    const float4* __restrict__ wvec = ws + (size_t)b * S;    // divergent gathers

    const float* q = xyz1 + (size_t)b * 3 * N;
    float x1 = q[n], y1 = q[n + N], z1 = q[n + 2 * N];
    float ssrc = __fadd_rn(__fadd_rn(__fmul_rn(x1, x1), __fmul_rn(y1, y1)),
                           __fmul_rn(z1, z1));
    // screen-only constants (proxy zone; phase C refine is exact)
    float c = ssrc + 0.25f;  // bias keeps packed keys > 0
    float nx2 = -2.0f * x1, ny2 = -2.0f * y1, nz2 = -2.0f * z1;

    // ---- Phase A: SMEM-streamed group scan; keep 5 best (min | gid) ----
    float g0 = 3.0e38f, g1 = 3.0e38f, g2 = 3.0e38f, g3 = 3.0e38f, g4 = 3.0e38f;
#pragma unroll 2
    for (int g = 0; g < 64; ++g) {
        float4 p[8];
#pragma unroll
        for (int j = 0; j < 8; ++j) p[j] = wtab[g * 8 + j];  // uniform -> s_load
        float e[8];
#pragma unroll
        for (int j = 0; j < 8; ++j)
            e[j] = fmaf(nx2, p[j].x,
                        fmaf(ny2, p[j].y, fmaf(nz2, p[j].z, p[j].w)));
        // min tree (8 -> 1): nested fminf fuses to v_min3_f32
        float mA = fminf(fminf(e[0], e[1]), e[2]);
        float mB = fminf(fminf(e[3], e[4]), e[5]);
        float mC = fminf(fminf(mA, mB), e[6]);
        float gm = fminf(mC, e[7]);
        float gkey = __uint_as_float((__float_as_uint(gm + c) & 0xFFFFFFC0u) |
                                     (uint32_t)g);
        INS5(gkey);
    }

    // ---- Phase C: global/L1 divergent gathers; proxy 6-slot screen ----
    float m0 = 3.0e38f, m1 = 3.0e38f, m2 = 3.0e38f,
          m3 = 3.0e38f, m4 = 3.0e38f, m5 = 3.0e38f;
    float gkeys[5] = {g0, g1, g2, g3, g4};
#pragma unroll
    for (int t = 0; t < 5; ++t) {
        int gbase = (int)(__float_as_uint(gkeys[t]) & 63u) << 3;
#pragma unroll
        for (int j = 0; j < 8; ++j) {
            float4 p = wvec[gbase + j];  // divergent gather, L1-resident
            float e2 = fmaf(nx2, p.x,
                            fmaf(ny2, p.y, fmaf(nz2, p.z, p.w + c)));
            float k = __uint_as_float((__float_as_uint(e2) & 0xFFFFFE00u) |
                                      (uint32_t)(gbase + j));
            INS6(k);
        }
    }

    // ---- Refine: re-score 6 survivors exactly, sort by (d, idx) ----
    int gi[6];
    float dd[6];
    gi[0] = (int)(__float_as_uint(m0) & 511u);
    gi[1] = (int)(__float_as_uint(m1) & 511u);
    gi[2] = (int)(__float_as_uint(m2) & 511u);
    gi[3] = (int)(__float_as_uint(m3) & 511u);
    gi[4] = (int)(__float_as_uint(m4) & 511u);
    gi[5] = (int)(__float_as_uint(m5) & 511u);
#pragma unroll
    for (int j = 0; j < 6; ++j) dd[j] = ref_d(x1, y1, z1, ssrc, wvec[gi[j]]);

#pragma unroll
    for (int pp = 0; pp < 3; ++pp)
#pragma unroll
        for (int i = 4; i >= pp; --i) CAS(dd[i], gi[i], dd[i + 1], gi[i + 1]);

    // Replicate reference weight/interp chain in fp32, nearest-first order
    const float EPS32 = 1e-8f;
    float r0 = __fdiv_rn(1.0f, __fadd_rn(dd[0], EPS32));
    float r1 = __fdiv_rn(1.0f, __fadd_rn(dd[1], EPS32));
    float r2 = __fdiv_rn(1.0f, __fadd_rn(dd[2], EPS32));
    float rs = __fadd_rn(__fadd_rn(r0, r1), r2);
    float w0 = __fdiv_rn(r0, rs);
    float w1 = __fdiv_rn(r1, rs);
    float w2 = __fdiv_rn(r2, rs);
    const float* f = points2 + (size_t)b * S;  // D = 1
    float interp = __fadd_rn(__fadd_rn(__fmul_rn(f[gi[0]], w0), __fmul_rn(f[gi[1]], w1)),
                             __fmul_rn(f[gi[2]], w2));
    float t = tanhf(interp);
    out[((size_t)b << 16) | (uint32_t)n] = __fmul_rn(__fadd_rn(t, 1.0f), 0.5f);
}

extern "C" void kernel_launch(void* const* d_in, const int* in_sizes, int n_in,
                              void* d_out, int out_size, void* d_ws, size_t ws_size,
                              hipStream_t stream) {
    const float* xyz1 = (const float*)d_in[0];
    const float* xyz2 = (const float*)d_in[1];
    const float* points2 = (const float*)d_in[2];
    float* out = (float*)d_out;
    float4* ws = (float4*)d_ws;  // B*S*16 = 32 KB

    prep_kernel<<<(B * S + 255) / 256, 256, 0, stream>>>(xyz2, ws);
    knn3_kernel<<<(B * N) / 256, 256, 0, stream>>>(xyz1, points2, ws, out);
}

// Round 12
// 40.987 us; speedup vs baseline: 1.4639x; 1.0825x over previous
//
#include <hip/hip_runtime.h>
#include <stdint.h>

// AeTransformer_44839458570443: 3-NN inverse-distance interpolation + (tanh+1)/2.
// xyz1: [B,3,N] fp32, xyz2: [B,3,S] fp32, points2: [B,1,S] fp32 -> out [B,N] fp32.
//
// Selection bit-matches the reference fp32 expanded distance
//   d = (-2*((x*x'+y*y')+z*z') + ||q||^2) + ||p||^2   (fp32, no FMA)
// ordered by (d, index).
//
// R11 (SMEM-streamed group scan) was latency-stalled at 4 waves/SIMD
// (VALUBusy 57%), but needs only 32 VGPRs -> room for 8 waves/SIMD.
// Round 12: 2-way CANDIDATE SPLIT across wave pairs at 1 query/lane:
//   wave h of a pair scans groups [32h, 32h+32) via s_load (K$, scalar pipe);
//   8192 waves total = 8 waves/SIMD for latency hiding. MERGE: 5 group-keys
//   per query through 5 KB LDS + one barrier + INS5 (halves disjoint, keys
//   unique -> min-5 of union == merge of per-half min-5s == R11's set).
//   h=1 waves retire after the barrier (R4-proven); h=0 runs phase C.
// PHASE A (proxy): per group of 8, 3-FMA distances + min tree -> group min;
//   keep 5 best (group-min | gid) keys. Lemma: at most 3 groups can have
//   min <= d3 -> top-3 lives in best-3 groups; 5 kept for proxy margin.
// PHASE C (global/L1 divergent gathers; R8-R11-proven, 0 bank conflicts):
//   FMA-proxy rescan of the 40 survivors, 9-bit-quantized 6-slot screen,
//   exact replicated ref_d on 6, (d,idx) sort, replicated fp32 weight chain.
static constexpr int B = 4;
static constexpr int N = 65536;
static constexpr int S = 512;

__global__ __launch_bounds__(256) void prep_kernel(const float* __restrict__ xyz2,
                                                   float4* __restrict__ ws) {
    int t = blockIdx.x * 256 + threadIdx.x;
    if (t >= B * S) return;
    int b = t >> 9, s = t & 511;
    const float* p = xyz2 + (size_t)b * 3 * S;
    float x = p[s], y = p[s + S], z = p[s + 2 * S];
    float c = __fadd_rn(__fadd_rn(__fmul_rn(x, x), __fmul_rn(y, y)), __fmul_rn(z, z));
    ws[t] = make_float4(x, y, z, c);
}

// Reference-replicated fp32 distance (numpy order, no contraction)
__device__ __forceinline__ float ref_d(float x1, float y1, float z1, float ssrc, float4 p) {
    float dot = __fadd_rn(__fadd_rn(__fmul_rn(x1, p.x), __fmul_rn(y1, p.y)),
                          __fmul_rn(z1, p.z));
    float t = __fmul_rn(dot, -2.0f);
    return __fadd_rn(__fadd_rn(t, ssrc), p.w);
}

#define CAS(da_, ia_, db_, ib_)                                     \
    {                                                               \
        bool sw_ = (db_ < da_) || ((db_ == da_) && (ib_ < ia_));    \
        float tda_ = sw_ ? db_ : da_;                               \
        int tia_ = sw_ ? ib_ : ia_;                                 \
        db_ = sw_ ? da_ : db_;                                      \
        ib_ = sw_ ? ia_ : ib_;                                      \
        da_ = tda_;                                                 \
        ia_ = tia_;                                                 \
    }

#define INS5(k)                                                     \
    {                                                               \
        float t4 = __builtin_amdgcn_fmed3f(g3, (k), g4);            \
        float t3 = __builtin_amdgcn_fmed3f(g2, (k), g3);            \
        float t2 = __builtin_amdgcn_fmed3f(g1, (k), g2);            \
        float t1 = __builtin_amdgcn_fmed3f(g0, (k), g1);            \
        g0 = fminf(g0, (k));                                        \
        g1 = t1; g2 = t2; g3 = t3; g4 = t4;                         \
    }

#define INS6(k)                                                     \
    {                                                               \
        float t5 = __builtin_amdgcn_fmed3f(m4, (k), m5);            \
        float t4 = __builtin_amdgcn_fmed3f(m3, (k), m4);            \
        float t3 = __builtin_amdgcn_fmed3f(m2, (k), m3);            \
        float t2 = __builtin_amdgcn_fmed3f(m1, (k), m2);            \
        float t1 = __builtin_amdgcn_fmed3f(m0, (k), m1);            \
        m0 = fminf(m0, (k));                                        \
        m1 = t1; m2 = t2; m3 = t3; m4 = t4; m5 = t5;                \
    }

__global__ __launch_bounds__(256, 8) void knn3_kernel(const float* __restrict__ xyz1,
                                                      const float* __restrict__ points2,
                                                      const float4* __restrict__ ws,
                                                      float* __restrict__ out) {
    __shared__ float keys_sh[5][256];  // 5 KB group-key exchange
    const int tid = threadIdx.x;
    const int lane = tid & 63;
    const int pr = tid >> 7;           // wave-pair id within block (0,1)
    const int b = blockIdx.x >> 9;     // 512 blocks per batch
    const int n = ((blockIdx.x & 511) << 7) + (pr << 6) + lane;

    // Wave-uniform values laundered into SGPRs so the phase-A table reads
    // stay on the scalar (s_load / K$) path.
    const int b_u = __builtin_amdgcn_readfirstlane(b);
    const int h_u = __builtin_amdgcn_readfirstlane((tid >> 6) & 1);
    const float4* __restrict__ wtab = ws + (size_t)b_u * S;  // uniform scan
    const float4* __restrict__ wvec = ws + (size_t)b * S;    // divergent gathers

    const float* q = xyz1 + (size_t)b * 3 * N;
    float x1 = q[n], y1 = q[n + N], z1 = q[n + 2 * N];
    float ssrc = __fadd_rn(__fadd_rn(__fmul_rn(x1, x1), __fmul_rn(y1, y1)),
                           __fmul_rn(z1, z1));
    // screen-only constants (proxy zone; phase C refine is exact)
    float c = ssrc + 0.25f;  // bias keeps packed keys > 0
    float nx2 = -2.0f * x1, ny2 = -2.0f * y1, nz2 = -2.0f * z1;

    // ---- Phase A: scan own 32 groups via s_load; keep 5 best (min|gid) ----
    float g0 = 3.0e38f, g1 = 3.0e38f, g2 = 3.0e38f, g3 = 3.0e38f, g4 = 3.0e38f;
    const int gid0 = h_u << 5;
#pragma unroll 2
    for (int g = 0; g < 32; ++g) {
        const int gid = gid0 + g;
        float4 p[8];
#pragma unroll
        for (int j = 0; j < 8; ++j) p[j] = wtab[gid * 8 + j];  // uniform -> s_load
        float e[8];
#pragma unroll
        for (int j = 0; j < 8; ++j)
            e[j] = fmaf(nx2, p[j].x,
                        fmaf(ny2, p[j].y, fmaf(nz2, p[j].z, p[j].w)));
        float mA = fminf(fminf(e[0], e[1]), e[2]);
        float mB = fminf(fminf(e[3], e[4]), e[5]);
        float mC = fminf(fminf(mA, mB), e[6]);
        float gm = fminf(mC, e[7]);
        float gkey = __uint_as_float((__float_as_uint(gm + c) & 0xFFFFFFC0u) |
                                     (uint32_t)gid);
        INS5(gkey);
    }

    // ---- publish keys; merge within wave pair ----
    keys_sh[0][tid] = g0;
    keys_sh[1][tid] = g1;
    keys_sh[2][tid] = g2;
    keys_sh[3][tid] = g3;
    keys_sh[4][tid] = g4;
    __syncthreads();
    if (h_u) return;  // half-1 waves done (R4-proven: return after barrier)

    {
        const int ptid = tid ^ 64;  // partner wave, same lane
        float pk0 = keys_sh[0][ptid], pk1 = keys_sh[1][ptid],
              pk2 = keys_sh[2][ptid], pk3 = keys_sh[3][ptid],
              pk4 = keys_sh[4][ptid];
        INS5(pk0); INS5(pk1); INS5(pk2); INS5(pk3); INS5(pk4);
    }

    // ---- Phase C: global/L1 divergent gathers; proxy 6-slot screen ----
    float m0 = 3.0e38f, m1 = 3.0e38f, m2 = 3.0e38f,
          m3 = 3.0e38f, m4 = 3.0e38f, m5 = 3.0e38f;
    float gkeys[5] = {g0, g1, g2, g3, g4};
#pragma unroll
    for (int t = 0; t < 5; ++t) {
        int gbase = (int)(__float_as_uint(gkeys[t]) & 63u) << 3;
#pragma unroll
        for (int j = 0; j < 8; ++j) {
            float4 p = wvec[gbase + j];  // divergent gather, L1-resident
            float e2 = fmaf(nx2, p.x,
                            fmaf(ny2, p.y, fmaf(nz2, p.z, p.w + c)));
            float k = __uint_as_float((__float_as_uint(e2) & 0xFFFFFE00u) |
                                      (uint32_t)(gbase + j));
            INS6(k);
        }
    }

    // ---- Refine: re-score 6 survivors exactly, sort by (d, idx) ----
    int gi[6];
    float dd[6];
    gi[0] = (int)(__float_as_uint(m0) & 511u);
    gi[1] = (int)(__float_as_uint(m1) & 511u);
    gi[2] = (int)(__float_as_uint(m2) & 511u);
    gi[3] = (int)(__float_as_uint(m3) & 511u);
    gi[4] = (int)(__float_as_uint(m4) & 511u);
    gi[5] = (int)(__float_as_uint(m5) & 511u);
#pragma unroll
    for (int j = 0; j < 6; ++j) dd[j] = ref_d(x1, y1, z1, ssrc, wvec[gi[j]]);

#pragma unroll
    for (int pp = 0; pp < 3; ++pp)
#pragma unroll
        for (int i = 4; i >= pp; --i) CAS(dd[i], gi[i], dd[i + 1], gi[i + 1]);

    // Replicate reference weight/interp chain in fp32, nearest-first order
    const float EPS32 = 1e-8f;
    float r0 = __fdiv_rn(1.0f, __fadd_rn(dd[0], EPS32));
    float r1 = __fdiv_rn(1.0f, __fadd_rn(dd[1], EPS32));
    float r2 = __fdiv_rn(1.0f, __fadd_rn(dd[2], EPS32));
    float rs = __fadd_rn(__fadd_rn(r0, r1), r2);
    float w0 = __fdiv_rn(r0, rs);
    float w1 = __fdiv_rn(r1, rs);
    float w2 = __fdiv_rn(r2, rs);
    const float* f = points2 + (size_t)b * S;  // D = 1
    float interp = __fadd_rn(__fadd_rn(__fmul_rn(f[gi[0]], w0), __fmul_rn(f[gi[1]], w1)),
                             __fmul_rn(f[gi[2]], w2));
    float t = tanhf(interp);
    out[((size_t)b << 16) | (uint32_t)n] = __fmul_rn(__fadd_rn(t, 1.0f), 0.5f);
}

extern "C" void kernel_launch(void* const* d_in, const int* in_sizes, int n_in,
                              void* d_out, int out_size, void* d_ws, size_t ws_size,
                              hipStream_t stream) {
    const float* xyz1 = (const float*)d_in[0];
    const float* xyz2 = (const float*)d_in[1];
    const float* points2 = (const float*)d_in[2];
    float* out = (float*)d_out;
    float4* ws = (float4*)d_ws;  // B*S*16 = 32 KB

    prep_kernel<<<(B * S + 255) / 256, 256, 0, stream>>>(xyz2, ws);
    // 2048 blocks x 256 threads: wave pairs share 64 queries, split candidates
    knn3_kernel<<<(B * N) / 128, 256, 0, stream>>>(xyz1, points2, ws, out);
}